// Round 1
// baseline (2332.796 us; speedup 1.0000x reference)
//
#include <hip/hip_runtime.h>

typedef unsigned short u16;
typedef __attribute__((ext_vector_type(8))) short short8;
typedef __attribute__((ext_vector_type(4))) float floatx4;

#define DEV static __device__ __forceinline__

DEV u16 f2bf(float f) {
    union { float f; unsigned u; } v; v.f = f;
    unsigned r = v.u + 0x7fff + ((v.u >> 16) & 1);
    return (u16)(r >> 16);
}
DEV float bf2f(u16 h) {
    union { unsigned u; float f; } v; v.u = ((unsigned)h) << 16;
    return v.f;
}

DEV void load_lds16(const u16* g, u16* l) {
    __builtin_amdgcn_global_load_lds(
        (const __attribute__((address_space(1))) void*)g,
        (__attribute__((address_space(3))) void*)l, 16, 0, 0);
}

#define FLAG_BF16 1
#define FLAG_CF   2
#define FLAG_AT   4

// ---------------------------------------------------------------------------
// NT GEMM: C[M][256] = A[M][K] * BT[256][K]^T + bias.  bf16 in, f32 acc.
// 128x128 tile, BK=32, 256 threads, m97 structure (global_load_lds width 16).
// Optional split-K (KS>1) accumulates via atomicAdd into f32 [M][256] buffer.
// ---------------------------------------------------------------------------
__global__ __launch_bounds__(256, 2) void gemm_nt(
    const u16* __restrict__ A, const u16* __restrict__ BT,
    const float* __restrict__ bias,
    u16* __restrict__ obf, float* __restrict__ ocf, float* __restrict__ oat,
    int M, int K, int KS, int flags, int HW,
    long sA, long sBF, long sCF, long sAT)
{
    __shared__ u16 Al[4096];   // layout [quad][row(128)][8]
    __shared__ u16 Bl[4096];
    const int tid = threadIdx.x, lane = tid & 63, w = tid >> 6;
    const int wr = w & 1, wc = w >> 1;
    const int col16 = lane & 15, quad = (lane >> 4) & 3;
    const int mt = blockIdx.x, nt = blockIdx.y & 1, ks = blockIdx.y >> 1, z = blockIdx.z;
    const int m0 = mt * 128, n0 = nt * 128;
    const u16* Ab = A + (size_t)z * sA;
    const int Kper = K / KS;
    const int kbeg = ks * Kper;
    const floatx4 fz = {0.f, 0.f, 0.f, 0.f};

    floatx4 acc[4][4];
#pragma unroll
    for (int i = 0; i < 4; ++i)
#pragma unroll
        for (int j = 0; j < 4; ++j) acc[i][j] = fz;

    for (int kb = 0; kb < Kper; kb += 32) {
        const int k0 = kbeg + kb;
        __syncthreads();
#pragma unroll
        for (int i = 0; i < 2; ++i) {
            int cc = w * 2 + i;
            int q = cc >> 1;
            int row = (cc & 1) * 64 + lane;
            int rg = m0 + row; rg = rg < M ? rg : (M - 1);
            load_lds16(Ab + (size_t)rg * K + k0 + q * 8, &Al[cc * 512]);
            int nr = n0 + row;   // always < 256
            load_lds16(BT + (size_t)nr * K + k0 + q * 8, &Bl[cc * 512]);
        }
        __syncthreads();
        short8 af[4], bfr[4];
#pragma unroll
        for (int i = 0; i < 4; ++i)
            af[i] = *(const short8*)&Al[(quad * 128 + wr * 64 + i * 16 + col16) * 8];
#pragma unroll
        for (int j = 0; j < 4; ++j)
            bfr[j] = *(const short8*)&Bl[(quad * 128 + wc * 64 + j * 16 + col16) * 8];
#pragma unroll
        for (int i = 0; i < 4; ++i)
#pragma unroll
            for (int j = 0; j < 4; ++j)
                acc[i][j] = __builtin_amdgcn_mfma_f32_16x16x32_bf16(af[i], bfr[j], acc[i][j], 0, 0, 0);
    }

#pragma unroll
    for (int j = 0; j < 4; ++j) {
        int gcol = n0 + wc * 64 + j * 16 + col16;
        float bv = (ks == 0) ? bias[gcol] : 0.f;
#pragma unroll
        for (int i = 0; i < 4; ++i) {
            int rowb = m0 + wr * 64 + i * 16 + quad * 4;
#pragma unroll
            for (int r = 0; r < 4; ++r) {
                int row = rowb + r;
                if (row < M) {
                    float v = acc[i][j][r] + bv;
                    if (flags & FLAG_BF16) obf[(size_t)z * sBF + (size_t)row * 256 + gcol] = f2bf(v);
                    if (flags & FLAG_CF)   ocf[(size_t)z * sCF + (size_t)gcol * HW + row] = v;
                    if (flags & FLAG_AT)   atomicAdd(&oat[(size_t)z * sAT + (size_t)row * 256 + gcol], v);
                }
            }
        }
    }
}

// ---------------------------------------------------------------------------
// Flash attention, one block per (b, shot, 128-row Q tile). C = D = 256.
// Scores are tiny (|s|<~0.5) so exp() without max-subtraction is safe.
// Output: atomicAdd of (softmax @ V)/5 into d_out channel-first [b][256+c][l].
// ---------------------------------------------------------------------------
__global__ __launch_bounds__(256, 2) void flash_attn(
    const u16* __restrict__ Q,   // [8][L][256]
    const u16* __restrict__ K,   // [40][L][256]
    const u16* __restrict__ VT,  // [40][256][L]
    float* __restrict__ outp, int L)
{
    __shared__ u16 Kl[8192];     // [cg(32)][row(32)][8]
    __shared__ u16 Vt[8192];     // [c(256)][m(32)]
    __shared__ u16 Pl[4096];     // [l(128)][m(32)]
    __shared__ float lrun[128];
    const int tid = threadIdx.x, lane = tid & 63, w = tid >> 6;
    const int col16 = lane & 15, quad = (lane >> 4) & 3;
    const int b = blockIdx.z, sh = blockIdx.y, sb = b * 5 + sh;
    const int q0 = blockIdx.x * 128;
    const u16* Qb = Q + (size_t)b * L * 256;
    const u16* Kb = K + (size_t)sb * L * 256;
    const u16* Vb = VT + (size_t)sb * 256 * L;
    const floatx4 fz = {0.f, 0.f, 0.f, 0.f};

    short8 qf[2][8];
#pragma unroll
    for (int lt = 0; lt < 2; ++lt) {
        int row = q0 + w * 32 + lt * 16 + col16; row = row < L ? row : (L - 1);
#pragma unroll
        for (int kc = 0; kc < 8; ++kc)
            qf[lt][kc] = *(const short8*)(Qb + (size_t)row * 256 + kc * 32 + quad * 8);
    }

    floatx4 acc[8][4];
#pragma unroll
    for (int lr = 0; lr < 8; ++lr)
#pragma unroll
        for (int ct = 0; ct < 4; ++ct) acc[lr][ct] = fz;
    float rsum[2][4] = {{0.f,0.f,0.f,0.f},{0.f,0.f,0.f,0.f}};

    const int nkt = (L + 31) >> 5;
    for (int kt = 0; kt < nkt; ++kt) {
        __syncthreads();
#pragma unroll
        for (int i = 0; i < 4; ++i) {
            int cc = w * 4 + i;
            int cg = cc * 2 + (lane >> 5);
            int row = lane & 31;
            int rg = kt * 32 + row; rg = rg < L ? rg : (L - 1);
            load_lds16(Kb + (size_t)rg * 256 + cg * 8, &Kl[cc * 512]);
            int c = cc * 16 + (lane >> 2);
            int m0 = (lane & 3) * 8;
            load_lds16(Vb + (size_t)c * L + kt * 32 + m0, &Vt[cc * 512]);  // slight tail overrun covered by ws pad
        }
        __syncthreads();
        floatx4 s00 = fz, s01 = fz, s10 = fz, s11 = fz;
#pragma unroll
        for (int kc = 0; kc < 8; ++kc) {
            short8 b0 = *(const short8*)&Kl[((kc * 4 + quad) * 32 + col16) * 8];
            short8 b1 = *(const short8*)&Kl[((kc * 4 + quad) * 32 + 16 + col16) * 8];
            s00 = __builtin_amdgcn_mfma_f32_16x16x32_bf16(qf[0][kc], b0, s00, 0, 0, 0);
            s01 = __builtin_amdgcn_mfma_f32_16x16x32_bf16(qf[0][kc], b1, s01, 0, 0, 0);
            s10 = __builtin_amdgcn_mfma_f32_16x16x32_bf16(qf[1][kc], b0, s10, 0, 0, 0);
            s11 = __builtin_amdgcn_mfma_f32_16x16x32_bf16(qf[1][kc], b1, s11, 0, 0, 0);
        }
        const bool v0 = (kt * 32 + col16) < L;
        const bool v1 = (kt * 32 + 16 + col16) < L;
        float p0[4], p1[4], p2[4], p3[4];
#pragma unroll
        for (int r = 0; r < 4; ++r) {
            p0[r] = v0 ? __expf(s00[r] * 0.0625f) : 0.f;
            p1[r] = v1 ? __expf(s01[r] * 0.0625f) : 0.f;
            p2[r] = v0 ? __expf(s10[r] * 0.0625f) : 0.f;
            p3[r] = v1 ? __expf(s11[r] * 0.0625f) : 0.f;
        }
#pragma unroll
        for (int r = 0; r < 4; ++r) {
            float v = p0[r] + p1[r];
            v += __shfl_xor(v, 1); v += __shfl_xor(v, 2); v += __shfl_xor(v, 4); v += __shfl_xor(v, 8);
            rsum[0][r] += v;
            float u = p2[r] + p3[r];
            u += __shfl_xor(u, 1); u += __shfl_xor(u, 2); u += __shfl_xor(u, 4); u += __shfl_xor(u, 8);
            rsum[1][r] += u;
        }
#pragma unroll
        for (int r = 0; r < 4; ++r) {
            int l0 = w * 32 + quad * 4 + r;
            Pl[l0 * 32 + col16]        = f2bf(p0[r]);
            Pl[l0 * 32 + 16 + col16]   = f2bf(p1[r]);
            Pl[(l0 + 16) * 32 + col16]      = f2bf(p2[r]);
            Pl[(l0 + 16) * 32 + 16 + col16] = f2bf(p3[r]);
        }
        __syncthreads();
#pragma unroll
        for (int ct = 0; ct < 4; ++ct) {
            short8 bv = *(const short8*)&Vt[(w * 64 + ct * 16 + col16) * 32 + quad * 8];
#pragma unroll
            for (int lr = 0; lr < 8; ++lr) {
                short8 ap = *(const short8*)&Pl[(lr * 16 + col16) * 32 + quad * 8];
                acc[lr][ct] = __builtin_amdgcn_mfma_f32_16x16x32_bf16(ap, bv, acc[lr][ct], 0, 0, 0);
            }
        }
    }

    if (col16 == 0) {
#pragma unroll
        for (int lt = 0; lt < 2; ++lt)
#pragma unroll
            for (int r = 0; r < 4; ++r) lrun[w * 32 + lt * 16 + quad * 4 + r] = rsum[lt][r];
    }
    __syncthreads();

#pragma unroll
    for (int lr = 0; lr < 8; ++lr) {
#pragma unroll
        for (int r = 0; r < 4; ++r) {
            int lloc = lr * 16 + quad * 4 + r;
            int l = q0 + lloc;
            if (l < L) {
                float sc = 0.2f / lrun[lloc];
#pragma unroll
                for (int ct = 0; ct < 4; ++ct) {
                    int c = w * 64 + ct * 16 + col16;
                    atomicAdd(&outp[((size_t)b * 512 + 256 + c) * L + l], acc[lr][ct][r] * sc);
                }
            }
        }
    }
}

// ------------------- small glue kernels -------------------

// [z][C][HW] f32 -> [z][HW][C] bf16 (tiled 32x32)
__global__ void transp_cast(const float* __restrict__ in, u16* __restrict__ out, int C, int HW) {
    __shared__ float t[32][33];
    int z = blockIdx.z;
    int p0 = blockIdx.x * 32, c0 = blockIdx.y * 32;
    int tx = threadIdx.x & 31, ty = threadIdx.x >> 5;
    const float* ib = in + (size_t)z * C * HW;
    u16* ob = out + (size_t)z * HW * C;
#pragma unroll
    for (int i = 0; i < 4; ++i) {
        int c = c0 + ty + i * 8, p = p0 + tx;
        t[ty + i * 8][tx] = (p < HW) ? ib[(size_t)c * HW + p] : 0.f;
    }
    __syncthreads();
#pragma unroll
    for (int i = 0; i < 4; ++i) {
        int p = p0 + ty + i * 8, c = c0 + tx;
        if (p < HW) ob[(size_t)p * C + c] = f2bf(t[tx][ty + i * 8]);
    }
}

// [z][L][256] bf16 -> [z][256][L] bf16
__global__ void transp_bf(const u16* __restrict__ in, u16* __restrict__ out, int L) {
    __shared__ u16 t[32][33];
    int z = blockIdx.z;
    int l0 = blockIdx.x * 32, c0 = blockIdx.y * 32;
    int tx = threadIdx.x & 31, ty = threadIdx.x >> 5;
    const u16* ib = in + (size_t)z * L * 256;
    u16* ob = out + (size_t)z * 256 * L;
#pragma unroll
    for (int i = 0; i < 4; ++i) {
        int l = l0 + ty + i * 8;
        t[ty + i * 8][tx] = (l < L) ? ib[(size_t)l * 256 + c0 + tx] : (u16)0;
    }
    __syncthreads();
#pragma unroll
    for (int i = 0; i < 4; ++i) {
        int l = l0 + tx, c = c0 + ty + i * 8;
        if (l < L) ob[(size_t)c * L + l] = t[tx][ty + i * 8];
    }
}

__global__ void cast1d(const float* __restrict__ in, u16* __restrict__ out, long n) {
    long i = (long)blockIdx.x * 256 + threadIdx.x;
    if (i < n) out[i] = f2bf(in[i]);
}

// W [256][C][9] f32 -> [256][9][C] bf16
__global__ void reorder_w3(const float* __restrict__ in, u16* __restrict__ out, int C) {
    long i = (long)blockIdx.x * 256 + threadIdx.x;
    int co = (int)(i / (9L * C));
    int r = (int)(i % (9L * C));
    int t = r / C, c = r % C;
    out[i] = f2bf(in[((size_t)co * C + c) * 9 + t]);
}

// 3x3 s1 p1 im2col, C=256, channel-last bf16 -> rows [HW][9*256]
__global__ void im2col_s1(const u16* __restrict__ in, u16* __restrict__ out, int H, int Wd) {
    int z = blockIdx.y, p = blockIdx.x, c = threadIdx.x;
    int y = p / Wd, x = p % Wd;
    const u16* ib = in + (size_t)z * H * Wd * 256;
    u16* ob = out + ((size_t)z * H * Wd + p) * 2304;
#pragma unroll
    for (int t = 0; t < 9; ++t) {
        int ys = y + t / 3 - 1, xs = x + t % 3 - 1;
        u16 v = 0;
        if (ys >= 0 && ys < H && xs >= 0 && xs < Wd) v = ib[((size_t)ys * Wd + xs) * 256 + c];
        ob[t * 256 + c] = v;
    }
}

// 3x3 stride-2 p1 im2col, generic C, optional relu on read
__global__ void im2col_s2(const u16* __restrict__ in, u16* __restrict__ out,
                          int Hin, int Win, int Hout, int Wout, int C, int relu) {
    int z = blockIdx.y, p = blockIdx.x, tid = threadIdx.x;
    int oy = p / Wout, ox = p % Wout;
    const u16* ib = in + (size_t)z * Hin * Win * C;
    u16* ob = out + ((size_t)z * Hout * Wout + p) * (9L * C);
    for (int t = 0; t < 9; ++t) {
        int ys = oy * 2 + t / 3 - 1, xs = ox * 2 + t % 3 - 1;
        bool ok = (ys >= 0 && ys < Hin && xs >= 0 && xs < Win);
        for (int c = tid; c < C; c += 256) {
            u16 v = 0;
            if (ok) {
                v = ib[((size_t)ys * Win + xs) * C + c];
                if (relu && (v & 0x8000)) v = 0;
            }
            ob[(size_t)t * C + c] = v;
        }
    }
}

// big[p][c] += small[p/2-map][c]  (nearest 2x upsample add, in place, bf16)
__global__ void up2add(u16* __restrict__ big, const u16* __restrict__ small, int Hb, int Wb) {
    int z = blockIdx.y, p = blockIdx.x, c = threadIdx.x;
    int y = p / Wb, x = p % Wb;
    size_t bi = ((size_t)z * Hb * Wb + p) * 256 + c;
    size_t si = ((size_t)z * (Hb / 2) * (Wb / 2) + (size_t)(y >> 1) * (Wb / 2) + (x >> 1)) * 256 + c;
    big[bi] = f2bf(bf2f(big[bi]) + bf2f(small[si]));
}

// s[l][c] += pe(l,c), in place bf16
__global__ void add_pe(u16* __restrict__ s, int L) {
    int z = blockIdx.y, l = blockIdx.x, c = threadIdx.x;
    size_t i = ((size_t)z * L + l) * 256 + c;
    float arg = (float)l * expf(-0.035977892078031971f * (float)(c & ~1));
    float pe = (c & 1) ? cosf(arg) : sinf(arg);
    s[i] = f2bf(bf2f(s[i]) + pe);
}

// f32 [z][M][256] -> bf16 [z][M][256]; optional f32 channel-first d_out write
__global__ void cast_cl(const float* __restrict__ in, u16* __restrict__ outbf,
                        float* __restrict__ doutcf, int M, int writecf) {
    int z = blockIdx.y, p = blockIdx.x, c = threadIdx.x;
    float v = in[((size_t)z * M + p) * 256 + c];
    outbf[((size_t)z * M + p) * 256 + c] = f2bf(v);
    if (writecf) doutcf[(size_t)z * 512 * M + (size_t)c * M + p] = v;
}

// ---------------------------------------------------------------------------
extern "C" void kernel_launch(void* const* d_in, const int* in_sizes, int n_in,
                              void* d_out, int out_size, void* d_ws, size_t ws_size,
                              hipStream_t stream)
{
    (void)in_sizes; (void)n_in;
    const float* C3 = (const float*)d_in[0];
    const float* C4 = (const float*)d_in[1];
    const float* C5 = (const float*)d_in[2];
    const float* S3 = (const float*)d_in[3];
    const float* S4 = (const float*)d_in[4];
    const float* S5 = (const float*)d_in[5];
    const float* w31 = (const float*)d_in[6];  const float* b31 = (const float*)d_in[7];
    const float* w32 = (const float*)d_in[8];  const float* b32 = (const float*)d_in[9];
    const float* w41 = (const float*)d_in[10]; const float* b41 = (const float*)d_in[11];
    const float* w42 = (const float*)d_in[12]; const float* b42 = (const float*)d_in[13];
    const float* w51 = (const float*)d_in[14]; const float* b51 = (const float*)d_in[15];
    const float* w52 = (const float*)d_in[16]; const float* b52 = (const float*)d_in[17];
    const float* w6  = (const float*)d_in[18]; const float* b6  = (const float*)d_in[19];
    const float* w7  = (const float*)d_in[20]; const float* b7  = (const float*)d_in[21];
    const float* wq  = (const float*)d_in[22]; const float* bq  = (const float*)d_in[23];
    const float* wk  = (const float*)d_in[24]; const float* bk  = (const float*)d_in[25];
    float* out = (float*)d_out;

    char* base = (char*)d_ws;
    size_t off = 0;
    auto alloc = [&](size_t bytes) -> void* {
        void* r = base + off;
        off = (off + bytes + 255) & ~(size_t)255;
        return r;
    };

    // ---- workspace layout ----
    // Arena: X5t,S5t persistent; then a region later reused as im2col buffer.
    u16* X5t = (u16*)alloc((size_t)8  * 100  * 2048 * 2);
    u16* S5t = (u16*)alloc((size_t)40 * 100  * 2048 * 2);
    size_t alias_off = off;
    u16* X3t = (u16*)alloc((size_t)8  * 1600 * 512  * 2);
    u16* X4t = (u16*)alloc((size_t)8  * 400  * 1024 * 2);
    u16* S3t = (u16*)alloc((size_t)40 * 1600 * 512  * 2);
    u16* S4t = (u16*)alloc((size_t)40 * 400  * 1024 * 2);
    u16* imcol = (u16*)(base + alias_off);   // 59 MB needed <= 118 MB region

    u16* w31b = (u16*)alloc(256L * 512 * 2);
    u16* w41b = (u16*)alloc(256L * 1024 * 2);
    u16* w51b = (u16*)alloc(256L * 2048 * 2);
    u16* wqb  = (u16*)alloc(256L * 256 * 2);
    u16* wkb  = (u16*)alloc(256L * 256 * 2);
    u16* w32b = (u16*)alloc(256L * 9 * 256 * 2);
    u16* w42b = (u16*)alloc(256L * 9 * 256 * 2);
    u16* w52b = (u16*)alloc(256L * 9 * 256 * 2);
    u16* w6b  = (u16*)alloc(256L * 9 * 2048 * 2);
    u16* w7b  = (u16*)alloc(256L * 9 * 256 * 2);

    u16* P3x = (u16*)alloc((size_t)8  * 1600 * 256 * 2);
    u16* P4x = (u16*)alloc((size_t)8  * 400  * 256 * 2);
    u16* P5x = (u16*)alloc((size_t)8  * 100  * 256 * 2);
    u16* P3s = (u16*)alloc((size_t)40 * 1600 * 256 * 2);
    u16* P4s = (u16*)alloc((size_t)40 * 400  * 256 * 2);
    u16* P5s = (u16*)alloc((size_t)40 * 100  * 256 * 2);
    u16* q3  = (u16*)alloc((size_t)8 * 1600 * 256 * 2);
    u16* q4  = (u16*)alloc((size_t)8 * 400  * 256 * 2);
    u16* q5  = (u16*)alloc((size_t)8 * 100  * 256 * 2);
    u16* q6  = (u16*)alloc((size_t)8 * 25   * 256 * 2);
    u16* q7  = (u16*)alloc((size_t)8 * 9    * 256 * 2);
    u16* P6sb = (u16*)alloc((size_t)40 * 25 * 256 * 2);
    u16* P7sb = (u16*)alloc((size_t)40 * 9  * 256 * 2);
    float* P6xf = (float*)alloc((size_t)8  * 25 * 256 * 4);
    float* P6sf = (float*)alloc((size_t)40 * 25 * 256 * 4);
    float* P7xf = (float*)alloc((size_t)8  * 9  * 256 * 4);
    float* P7sf = (float*)alloc((size_t)40 * 9  * 256 * 4);
    u16* Qb = (u16*)alloc((size_t)8  * 1600 * 256 * 2);
    u16* Kb = (u16*)alloc((size_t)40 * 1600 * 256 * 2);
    u16* sPeT = (u16*)alloc((size_t)40 * 256 * 1600 * 2 + 4096);  // + tail pad for Vt overrun

    if (off > ws_size) return;  // visible failure rather than corruption

    hipMemsetAsync(d_out, 0, (size_t)out_size * 4, stream);
    hipMemsetAsync(P6xf, 0, (size_t)8  * 25 * 256 * 4, stream);
    hipMemsetAsync(P6sf, 0, (size_t)40 * 25 * 256 * 4, stream);
    hipMemsetAsync(P7xf, 0, (size_t)8  * 9  * 256 * 4, stream);
    hipMemsetAsync(P7sf, 0, (size_t)40 * 9  * 256 * 4, stream);

    // ---- weight prep ----
    cast1d<<<dim3(512),  256, 0, stream>>>(w31, w31b, 256L * 512);
    cast1d<<<dim3(1024), 256, 0, stream>>>(w41, w41b, 256L * 1024);
    cast1d<<<dim3(2048), 256, 0, stream>>>(w51, w51b, 256L * 2048);
    cast1d<<<dim3(256),  256, 0, stream>>>(wq, wqb, 256L * 256);
    cast1d<<<dim3(256),  256, 0, stream>>>(wk, wkb, 256L * 256);
    reorder_w3<<<dim3(2304),  256, 0, stream>>>(w32, w32b, 256);
    reorder_w3<<<dim3(2304),  256, 0, stream>>>(w42, w42b, 256);
    reorder_w3<<<dim3(2304),  256, 0, stream>>>(w52, w52b, 256);
    reorder_w3<<<dim3(18432), 256, 0, stream>>>(w6, w6b, 2048);
    reorder_w3<<<dim3(2304),  256, 0, stream>>>(w7, w7b, 256);

    // ---- input transposes to channel-last bf16 ----
    transp_cast<<<dim3(50, 16, 8),  256, 0, stream>>>(C3, X3t, 512, 1600);
    transp_cast<<<dim3(13, 32, 8),  256, 0, stream>>>(C4, X4t, 1024, 400);
    transp_cast<<<dim3(4,  64, 8),  256, 0, stream>>>(C5, X5t, 2048, 100);
    transp_cast<<<dim3(50, 16, 40), 256, 0, stream>>>(S3, S3t, 512, 1600);
    transp_cast<<<dim3(13, 32, 40), 256, 0, stream>>>(S4, S4t, 1024, 400);
    transp_cast<<<dim3(4,  64, 40), 256, 0, stream>>>(S5, S5t, 2048, 100);

    auto gemm = [&](const u16* A, const u16* BT, const float* bias,
                    u16* obf, float* ocf, float* oat,
                    int M, int K, int KS, int flags, int HW,
                    long sA, long sBF, long sCF, long sAT, int nb) {
        dim3 g((unsigned)((M + 127) / 128), (unsigned)(2 * KS), (unsigned)nb);
        gemm_nt<<<g, 256, 0, stream>>>(A, BT, bias, obf, ocf, oat, M, K, KS, flags, HW, sA, sBF, sCF, sAT);
    };

    // ---- lateral 1x1 convs ----
    gemm(X3t, w31b, b31, P3x, 0, 0, 1600, 512,  1, FLAG_BF16, 0, 1600L * 512,  1600L * 256, 0, 0, 8);
    gemm(X4t, w41b, b41, P4x, 0, 0, 400,  1024, 1, FLAG_BF16, 0, 400L * 1024,  400L * 256,  0, 0, 8);
    gemm(X5t, w51b, b51, P5x, 0, 0, 100,  2048, 1, FLAG_BF16, 0, 100L * 2048,  100L * 256,  0, 0, 8);
    gemm(S3t, w31b, b31, P3s, 0, 0, 1600, 512,  1, FLAG_BF16, 0, 1600L * 512,  1600L * 256, 0, 0, 40);
    gemm(S4t, w41b, b41, P4s, 0, 0, 400,  1024, 1, FLAG_BF16, 0, 400L * 1024,  400L * 256,  0, 0, 40);
    gemm(S5t, w51b, b51, P5s, 0, 0, 100,  2048, 1, FLAG_BF16, 0, 100L * 2048,  100L * 256,  0, 0, 40);

    const size_t lvl_off[5] = {0, 6553600, 8192000, 8601600, 8704000};

    // ---- P6/P7 heads (stride-2 convs, split-K GEMMs) ----
    im2col_s2<<<dim3(25, 8), 256, 0, stream>>>(X5t, imcol, 10, 10, 5, 5, 2048, 0);
    gemm(imcol, w6b, b6, 0, 0, P6xf, 25, 18432, 8, FLAG_AT, 0, 25L * 18432, 0, 0, 25L * 256, 8);
    im2col_s2<<<dim3(25, 40), 256, 0, stream>>>(S5t, imcol, 10, 10, 5, 5, 2048, 0);
    gemm(imcol, w6b, b6, 0, 0, P6sf, 25, 18432, 8, FLAG_AT, 0, 25L * 18432, 0, 0, 25L * 256, 40);
    cast_cl<<<dim3(25, 8),  256, 0, stream>>>(P6xf, q6, out + lvl_off[3], 25, 1);
    cast_cl<<<dim3(25, 40), 256, 0, stream>>>(P6sf, P6sb, 0, 25, 0);
    im2col_s2<<<dim3(9, 8), 256, 0, stream>>>(q6, imcol, 5, 5, 3, 3, 256, 1);
    gemm(imcol, w7b, b7, 0, 0, P7xf, 9, 2304, 4, FLAG_AT, 0, 9L * 2304, 0, 0, 9L * 256, 8);
    im2col_s2<<<dim3(9, 40), 256, 0, stream>>>(P6sb, imcol, 5, 5, 3, 3, 256, 1);
    gemm(imcol, w7b, b7, 0, 0, P7sf, 9, 2304, 4, FLAG_AT, 0, 9L * 2304, 0, 0, 9L * 256, 40);
    cast_cl<<<dim3(9, 8),  256, 0, stream>>>(P7xf, q7, out + lvl_off[4], 9, 1);
    cast_cl<<<dim3(9, 40), 256, 0, stream>>>(P7sf, P7sb, 0, 9, 0);

    // ---- query-side FPN ----
    up2add<<<dim3(400, 8),  256, 0, stream>>>(P4x, P5x, 20, 20);
    up2add<<<dim3(1600, 8), 256, 0, stream>>>(P3x, P4x, 40, 40);

    // ---- query-side 3x3 convs (write qx bf16 + d_out first half f32) ----
    im2col_s1<<<dim3(100, 8), 256, 0, stream>>>(P5x, imcol, 10, 10);
    gemm(imcol, w52b, b52, q5, out + lvl_off[2], 0, 100, 2304, 1, FLAG_BF16 | FLAG_CF, 100,
         100L * 2304, 100L * 256, 512L * 100, 0, 8);
    im2col_s1<<<dim3(400, 8), 256, 0, stream>>>(P4x, imcol, 20, 20);
    gemm(imcol, w42b, b42, q4, out + lvl_off[1], 0, 400, 2304, 1, FLAG_BF16 | FLAG_CF, 400,
         400L * 2304, 400L * 256, 512L * 400, 0, 8);
    im2col_s1<<<dim3(1600, 8), 256, 0, stream>>>(P3x, imcol, 40, 40);
    gemm(imcol, w32b, b32, q3, out + lvl_off[0], 0, 1600, 2304, 1, FLAG_BF16 | FLAG_CF, 1600,
         1600L * 2304, 1600L * 256, 512L * 1600, 0, 8);

    // ---- attention per level ----
    const int Ls[5] = {1600, 400, 100, 25, 9};
    u16* qbuf[5] = {q3, q4, q5, q6, q7};
    u16* sbuf[5] = {P3s, P4s, P5s, P6sb, P7sb};
    for (int lv = 0; lv < 5; ++lv) {
        int L = Ls[lv];
        add_pe<<<dim3(L, 40), 256, 0, stream>>>(sbuf[lv], L);
        transp_bf<<<dim3((L + 31) / 32, 8, 40), 256, 0, stream>>>(sbuf[lv], sPeT, L);
        gemm(qbuf[lv], wqb, bq, Qb, 0, 0, L, 256, 1, FLAG_BF16, 0, (long)L * 256, (long)L * 256, 0, 0, 8);
        gemm(sbuf[lv], wkb, bk, Kb, 0, 0, L, 256, 1, FLAG_BF16, 0, (long)L * 256, (long)L * 256, 0, 0, 40);
        flash_attn<<<dim3((L + 127) / 128, 5, 8), 256, 0, stream>>>(Qb, Kb, sPeT, out + lvl_off[lv], L);
    }
}

// Round 2
// 2320.944 us; speedup vs baseline: 1.0051x; 1.0051x over previous
//
#include <hip/hip_runtime.h>

typedef unsigned short u16;
typedef __attribute__((ext_vector_type(8))) short short8;
typedef __attribute__((ext_vector_type(4))) float floatx4;

#define DEV static __device__ __forceinline__

DEV u16 f2bf(float f) {
    union { float f; unsigned u; } v; v.f = f;
    unsigned r = v.u + 0x7fff + ((v.u >> 16) & 1);
    return (u16)(r >> 16);
}
DEV float bf2f(u16 h) {
    union { unsigned u; float f; } v; v.u = ((unsigned)h) << 16;
    return v.f;
}

DEV void load_lds16(const u16* g, u16* l) {
    __builtin_amdgcn_global_load_lds(
        (const __attribute__((address_space(1))) void*)g,
        (__attribute__((address_space(3))) void*)l, 16, 0, 0);
}

#define FLAG_BF16 1
#define FLAG_AT   4
#define FLAG_PV   8

// ---------------------------------------------------------------------------
// NT GEMM: C[M][256] = A[M][K] * BT[256][K]^T (+bias). bf16 in, f32 acc.
// 128x128 tile, BK=32, m97 staging. KS>1: split-K via atomicAdd (FLAG_AT).
// FLAG_PV: epilogue scales by 0.2/lsum[row] and atomicAdds into channel-last
//          f32 [b][M][256] (b = shot-batch z/5) — coalesced; transpose later.
// ---------------------------------------------------------------------------
__global__ __launch_bounds__(256, 2) void gemm_nt(
    const u16* __restrict__ A, const u16* __restrict__ BT,
    const float* __restrict__ bias,
    u16* __restrict__ obf, float* __restrict__ oat, const float* __restrict__ lsum,
    int M, int K, int KS, int flags, int zoff,
    long sA, long sBT, long sBF, long sAT)
{
    __shared__ u16 Al[4096];   // [quad][row(128)][8]
    __shared__ u16 Bl[4096];
    const int tid = threadIdx.x, lane = tid & 63, w = tid >> 6;
    const int wr = w & 1, wc = w >> 1;
    const int col16 = lane & 15, quad = (lane >> 4) & 3;
    const int mt = blockIdx.x, nt = blockIdx.y & 1, ks = blockIdx.y >> 1, z = blockIdx.z;
    const int sb = zoff + z;
    const int m0 = mt * 128, n0 = nt * 128;
    const u16* Ab = A + (size_t)z * sA;
    const u16* Bb = BT + (size_t)sb * sBT;
    const int Kper = K / KS;
    const int kbeg = ks * Kper;
    const floatx4 fz = {0.f, 0.f, 0.f, 0.f};

    floatx4 acc[4][4];
#pragma unroll
    for (int i = 0; i < 4; ++i)
#pragma unroll
        for (int j = 0; j < 4; ++j) acc[i][j] = fz;

    for (int kb = 0; kb < Kper; kb += 32) {
        const int k0 = kbeg + kb;
        __syncthreads();
#pragma unroll
        for (int i = 0; i < 2; ++i) {
            int cc = w * 2 + i;
            int q = cc >> 1;
            int row = (cc & 1) * 64 + lane;
            int rg = m0 + row; rg = rg < M ? rg : (M - 1);
            load_lds16(Ab + (size_t)rg * K + k0 + q * 8, &Al[cc * 512]);
            int nr = n0 + row;   // BT always has 256 rows
            load_lds16(Bb + (size_t)nr * K + k0 + q * 8, &Bl[cc * 512]);
        }
        __syncthreads();
        short8 af[4], bfr[4];
#pragma unroll
        for (int i = 0; i < 4; ++i)
            af[i] = *(const short8*)&Al[(quad * 128 + wr * 64 + i * 16 + col16) * 8];
#pragma unroll
        for (int j = 0; j < 4; ++j)
            bfr[j] = *(const short8*)&Bl[(quad * 128 + wc * 64 + j * 16 + col16) * 8];
#pragma unroll
        for (int i = 0; i < 4; ++i)
#pragma unroll
            for (int j = 0; j < 4; ++j)
                acc[i][j] = __builtin_amdgcn_mfma_f32_16x16x32_bf16(af[i], bfr[j], acc[i][j], 0, 0, 0);
    }

#pragma unroll
    for (int j = 0; j < 4; ++j) {
        int gcol = n0 + wc * 64 + j * 16 + col16;
        float bv = (bias && ks == 0) ? bias[gcol] : 0.f;
#pragma unroll
        for (int i = 0; i < 4; ++i) {
            int rowb = m0 + wr * 64 + i * 16 + quad * 4;
#pragma unroll
            for (int r = 0; r < 4; ++r) {
                int row = rowb + r;
                if (row < M) {
                    float v = acc[i][j][r] + bv;
                    if (flags & FLAG_BF16) obf[(size_t)z * sBF + (size_t)row * 256 + gcol] = f2bf(v);
                    if (flags & FLAG_AT)   atomicAdd(&oat[(size_t)z * sAT + (size_t)row * 256 + gcol], v);
                    if (flags & FLAG_PV) {
                        int bl = z / 5;   // chunk-local batch (zoff % 5 == 0)
                        float sc = 0.2f / lsum[(size_t)sb * 1664 + row];
                        atomicAdd(&oat[(size_t)bl * sAT + (size_t)row * 256 + gcol], v * sc);
                    }
                }
            }
        }
    }
}

// ---------------------------------------------------------------------------
// QK^T with fused exp epilogue. A=Q[b][M][256] (b=sb/5), BT=K[sb][M][256].
// Writes expS bf16 [z][M][Kpad] (cols >= M zero-padded) and atomically
// accumulates row sums (of the bf16-rounded values) into lsum[sb][row].
// ---------------------------------------------------------------------------
__global__ __launch_bounds__(256, 2) void gemm_qk_exp(
    const u16* __restrict__ Q, const u16* __restrict__ Km,
    u16* __restrict__ eS, float* __restrict__ lsum,
    int M, int Kpad, int zoff)
{
    __shared__ u16 Al[4096];
    __shared__ u16 Bl[4096];
    const int tid = threadIdx.x, lane = tid & 63, w = tid >> 6;
    const int wr = w & 1, wc = w >> 1;
    const int col16 = lane & 15, quad = (lane >> 4) & 3;
    const int mt = blockIdx.x, nt = blockIdx.y, z = blockIdx.z;
    const int sb = zoff + z;
    const int m0 = mt * 128, n0 = nt * 128;
    const u16* Ab = Q + (size_t)(sb / 5) * M * 256;
    const u16* Bb = Km + (size_t)sb * M * 256;
    u16* eSb = eS + (size_t)z * M * Kpad;
    const floatx4 fz = {0.f, 0.f, 0.f, 0.f};

    floatx4 acc[4][4];
#pragma unroll
    for (int i = 0; i < 4; ++i)
#pragma unroll
        for (int j = 0; j < 4; ++j) acc[i][j] = fz;

    for (int k0 = 0; k0 < 256; k0 += 32) {
        __syncthreads();
#pragma unroll
        for (int i = 0; i < 2; ++i) {
            int cc = w * 2 + i;
            int q = cc >> 1;
            int row = (cc & 1) * 64 + lane;
            int rg = m0 + row; rg = rg < M ? rg : (M - 1);
            load_lds16(Ab + (size_t)rg * 256 + k0 + q * 8, &Al[cc * 512]);
            int nr = n0 + row; nr = nr < M ? nr : (M - 1);
            load_lds16(Bb + (size_t)nr * 256 + k0 + q * 8, &Bl[cc * 512]);
        }
        __syncthreads();
        short8 af[4], bfr[4];
#pragma unroll
        for (int i = 0; i < 4; ++i)
            af[i] = *(const short8*)&Al[(quad * 128 + wr * 64 + i * 16 + col16) * 8];
#pragma unroll
        for (int j = 0; j < 4; ++j)
            bfr[j] = *(const short8*)&Bl[(quad * 128 + wc * 64 + j * 16 + col16) * 8];
#pragma unroll
        for (int i = 0; i < 4; ++i)
#pragma unroll
            for (int j = 0; j < 4; ++j)
                acc[i][j] = __builtin_amdgcn_mfma_f32_16x16x32_bf16(af[i], bfr[j], acc[i][j], 0, 0, 0);
    }

#pragma unroll
    for (int i = 0; i < 4; ++i) {
#pragma unroll
        for (int r = 0; r < 4; ++r) {
            int row = m0 + wr * 64 + i * 16 + quad * 4 + r;
            float s = 0.f;
#pragma unroll
            for (int j = 0; j < 4; ++j) {
                int gcol = n0 + wc * 64 + j * 16 + col16;
                float v = 0.f;
                if (row < M && gcol < M) v = __expf(acc[i][j][r] * 0.0625f);
                u16 h = f2bf(v);
                if (row < M) eSb[(size_t)row * Kpad + gcol] = h;
                s += bf2f(h);
            }
            s += __shfl_xor(s, 1); s += __shfl_xor(s, 2);
            s += __shfl_xor(s, 4); s += __shfl_xor(s, 8);
            if ((lane & 15) == 0 && row < M)
                atomicAdd(&lsum[(size_t)sb * 1664 + row], s);
        }
    }
}

// ------------------- glue kernels -------------------

// [z][C][HW] f32 -> [z][HW][C] bf16 (tiled 32x32)
__global__ void transp_cast(const float* __restrict__ in, u16* __restrict__ out, int C, int HW) {
    __shared__ float t[32][33];
    int z = blockIdx.z;
    int p0 = blockIdx.x * 32, c0 = blockIdx.y * 32;
    int tx = threadIdx.x & 31, ty = threadIdx.x >> 5;
    const float* ib = in + (size_t)z * C * HW;
    u16* ob = out + (size_t)z * HW * C;
#pragma unroll
    for (int i = 0; i < 4; ++i) {
        int c = c0 + ty + i * 8, p = p0 + tx;
        t[ty + i * 8][tx] = (p < HW) ? ib[(size_t)c * HW + p] : 0.f;
    }
    __syncthreads();
#pragma unroll
    for (int i = 0; i < 4; ++i) {
        int p = p0 + ty + i * 8, c = c0 + tx;
        if (p < HW) ob[(size_t)p * C + c] = f2bf(t[tx][ty + i * 8]);
    }
}

// support [z][L][256] bf16 -> V^T [z][256][Kpad] bf16, cols >= L zeroed
__global__ void transp_bf(const u16* __restrict__ in, u16* __restrict__ out, int L, int Kpad) {
    __shared__ u16 t[32][33];
    int z = blockIdx.z;
    int l0 = blockIdx.x * 32, c0 = blockIdx.y * 32;
    int tx = threadIdx.x & 31, ty = threadIdx.x >> 5;
    const u16* ib = in + (size_t)z * L * 256;
    u16* ob = out + (size_t)z * 256 * Kpad;
#pragma unroll
    for (int i = 0; i < 4; ++i) {
        int l = l0 + ty + i * 8;
        t[ty + i * 8][tx] = (l < L) ? ib[(size_t)l * 256 + c0 + tx] : (u16)0;
    }
    __syncthreads();
#pragma unroll
    for (int i = 0; i < 4; ++i) {
        int l = l0 + tx, c = c0 + ty + i * 8;
        ob[(size_t)c * Kpad + l] = t[tx][ty + i * 8];
    }
}

__global__ void cast1d(const float* __restrict__ in, u16* __restrict__ out, long n) {
    long i = (long)blockIdx.x * 256 + threadIdx.x;
    if (i < n) out[i] = f2bf(in[i]);
}

// W [256][C][9] f32 -> [256][9][C] bf16
__global__ void reorder_w3(const float* __restrict__ in, u16* __restrict__ out, int C) {
    long i = (long)blockIdx.x * 256 + threadIdx.x;
    int co = (int)(i / (9L * C));
    int r = (int)(i % (9L * C));
    int t = r / C, c = r % C;
    out[i] = f2bf(in[((size_t)co * C + c) * 9 + t]);
}

// 3x3 s1 p1 im2col, C=256, channel-last bf16 -> rows [z*HW][2304]
__global__ void im2col_s1(const u16* __restrict__ in, u16* __restrict__ out, int H, int Wd) {
    int z = blockIdx.y, p = blockIdx.x, c = threadIdx.x;
    int y = p / Wd, x = p % Wd;
    const u16* ib = in + (size_t)z * H * Wd * 256;
    u16* ob = out + ((size_t)z * H * Wd + p) * 2304;
#pragma unroll
    for (int t = 0; t < 9; ++t) {
        int ys = y + t / 3 - 1, xs = x + t % 3 - 1;
        u16 v = 0;
        if (ys >= 0 && ys < H && xs >= 0 && xs < Wd) v = ib[((size_t)ys * Wd + xs) * 256 + c];
        ob[t * 256 + c] = v;
    }
}

// 3x3 stride-2 p1 im2col, generic C, optional relu on read
__global__ void im2col_s2(const u16* __restrict__ in, u16* __restrict__ out,
                          int Hin, int Win, int Hout, int Wout, int C, int relu) {
    int z = blockIdx.y, p = blockIdx.x, tid = threadIdx.x;
    int oy = p / Wout, ox = p % Wout;
    const u16* ib = in + (size_t)z * Hin * Win * C;
    u16* ob = out + ((size_t)z * Hout * Wout + p) * (9L * C);
    for (int t = 0; t < 9; ++t) {
        int ys = oy * 2 + t / 3 - 1, xs = ox * 2 + t % 3 - 1;
        bool ok = (ys >= 0 && ys < Hin && xs >= 0 && xs < Win);
        for (int c = tid; c < C; c += 256) {
            u16 v = 0;
            if (ok) {
                v = ib[((size_t)ys * Win + xs) * C + c];
                if (relu && (v & 0x8000)) v = 0;
            }
            ob[(size_t)t * C + c] = v;
        }
    }
}

// big[p][c] += small[p/2-map][c]  (nearest 2x upsample add, in place, bf16)
__global__ void up2add(u16* __restrict__ big, const u16* __restrict__ small, int Hb, int Wb) {
    int z = blockIdx.y, p = blockIdx.x, c = threadIdx.x;
    int y = p / Wb, x = p % Wb;
    size_t bi = ((size_t)z * Hb * Wb + p) * 256 + c;
    size_t si = ((size_t)z * (Hb / 2) * (Wb / 2) + (size_t)(y >> 1) * (Wb / 2) + (x >> 1)) * 256 + c;
    big[bi] = f2bf(bf2f(big[bi]) + bf2f(small[si]));
}

// s[l][c] += pe(l,c), in place bf16
__global__ void add_pe(u16* __restrict__ s, int L) {
    int z = blockIdx.y, l = blockIdx.x, c = threadIdx.x;
    size_t i = ((size_t)z * L + l) * 256 + c;
    float arg = (float)l * expf(-0.035977892078031971f * (float)(c & ~1));
    float pe = (c & 1) ? cosf(arg) : sinf(arg);
    s[i] = f2bf(bf2f(s[i]) + pe);
}

// in f32 [z][M][256] -> optional bf16 qout (same layout, coalesced) and
// optional f32 d_out channel-first [z][512][M] at channel offset choff,
// via LDS 32x32 tile transpose (coalesced stores).
__global__ void cast_store(const float* __restrict__ in, u16* __restrict__ qout,
                           float* __restrict__ dout, int M, int choff) {
    __shared__ float t[32][33];
    int z = blockIdx.z, p0 = blockIdx.x * 32, c0 = blockIdx.y * 32;
    int tx = threadIdx.x & 31, ty = threadIdx.x >> 5;
#pragma unroll
    for (int i = 0; i < 4; ++i) {
        int p = p0 + ty + i * 8, c = c0 + tx;
        float v = 0.f;
        if (p < M) v = in[((size_t)z * M + p) * 256 + c];
        t[ty + i * 8][tx] = v;
        if (qout && p < M) qout[((size_t)z * M + p) * 256 + c] = f2bf(v);
    }
    __syncthreads();
    if (dout) {
#pragma unroll
        for (int i = 0; i < 4; ++i) {
            int p = p0 + tx, c = c0 + ty + i * 8;
            if (p < M) dout[((size_t)z * 512 + choff + c) * M + p] = t[tx][ty + i * 8];
        }
    }
}

// ---------------------------------------------------------------------------
extern "C" void kernel_launch(void* const* d_in, const int* in_sizes, int n_in,
                              void* d_out, int out_size, void* d_ws, size_t ws_size,
                              hipStream_t stream)
{
    (void)in_sizes; (void)n_in;
    const float* C3 = (const float*)d_in[0];
    const float* C4 = (const float*)d_in[1];
    const float* C5 = (const float*)d_in[2];
    const float* S3 = (const float*)d_in[3];
    const float* S4 = (const float*)d_in[4];
    const float* S5 = (const float*)d_in[5];
    const float* w31 = (const float*)d_in[6];  const float* b31 = (const float*)d_in[7];
    const float* w32 = (const float*)d_in[8];  const float* b32 = (const float*)d_in[9];
    const float* w41 = (const float*)d_in[10]; const float* b41 = (const float*)d_in[11];
    const float* w42 = (const float*)d_in[12]; const float* b42 = (const float*)d_in[13];
    const float* w51 = (const float*)d_in[14]; const float* b51 = (const float*)d_in[15];
    const float* w52 = (const float*)d_in[16]; const float* b52 = (const float*)d_in[17];
    const float* w6  = (const float*)d_in[18]; const float* b6  = (const float*)d_in[19];
    const float* w7  = (const float*)d_in[20]; const float* b7  = (const float*)d_in[21];
    const float* wq  = (const float*)d_in[22]; const float* bq  = (const float*)d_in[23];
    const float* wk  = (const float*)d_in[24]; const float* bk  = (const float*)d_in[25];
    float* out = (float*)d_out;

    char* base = (char*)d_ws;
    size_t off = 0;
    auto alloc = [&](size_t bytes) -> void* {
        void* r = base + off;
        off = (off + bytes + 255) & ~(size_t)255;
        return r;
    };

    // ---- arena (time-multiplexed): transposes -> imcol+convf32 -> expS+attnf32
    char* arena = (char*)alloc(117964800);
    u16* X3t = (u16*)(arena + 0);          //  8*1600*512*2  = 13,107,200
    u16* X4t = (u16*)(arena + 13107200);   //  8* 400*1024*2 =  6,553,600
    u16* S3t = (u16*)(arena + 19660800);   // 40*1600*512*2  = 65,536,000
    u16* S4t = (u16*)(arena + 85196800);   // 40* 400*1024*2 = 32,768,000
    u16*   imcol   = (u16*)(arena + 0);           // <= 58,982,400
    float* convf32 = (float*)(arena + 58982400);  // <= 13,107,200
    u16*   expS    = (u16*)(arena + 0);           // <= 106,496,000
    float* attnf32 = (float*)(arena + 106496000); // <=  6,553,600 (chunked) / level>=1 full

    u16* X5t = (u16*)alloc((size_t)8  * 100 * 2048 * 2);
    u16* S5t = (u16*)alloc((size_t)40 * 100 * 2048 * 2);

    u16* w31b = (u16*)alloc(256L * 512 * 2);
    u16* w41b = (u16*)alloc(256L * 1024 * 2);
    u16* w51b = (u16*)alloc(256L * 2048 * 2);
    u16* wqb  = (u16*)alloc(256L * 256 * 2);
    u16* wkb  = (u16*)alloc(256L * 256 * 2);
    u16* w32b = (u16*)alloc(256L * 9 * 256 * 2);
    u16* w42b = (u16*)alloc(256L * 9 * 256 * 2);
    u16* w52b = (u16*)alloc(256L * 9 * 256 * 2);
    u16* w6b  = (u16*)alloc(256L * 9 * 2048 * 2);
    u16* w7b  = (u16*)alloc(256L * 9 * 256 * 2);

    u16* P3x = (u16*)alloc((size_t)8  * 1600 * 256 * 2);
    u16* P4x = (u16*)alloc((size_t)8  * 400  * 256 * 2);
    u16* P5x = (u16*)alloc((size_t)8  * 100  * 256 * 2);
    u16* P3s = (u16*)alloc((size_t)40 * 1600 * 256 * 2);
    u16* P4s = (u16*)alloc((size_t)40 * 400  * 256 * 2);
    u16* P5s = (u16*)alloc((size_t)40 * 100  * 256 * 2);
    u16* q3  = (u16*)alloc((size_t)8 * 1600 * 256 * 2);
    u16* q4  = (u16*)alloc((size_t)8 * 400  * 256 * 2);
    u16* q5  = (u16*)alloc((size_t)8 * 100  * 256 * 2);
    u16* q6  = (u16*)alloc((size_t)8 * 25   * 256 * 2);
    u16* q7  = (u16*)alloc((size_t)8 * 9    * 256 * 2);
    u16* P6sb = (u16*)alloc((size_t)40 * 25 * 256 * 2);
    u16* P7sb = (u16*)alloc((size_t)40 * 9  * 256 * 2);
    float* P6xf = (float*)alloc((size_t)8  * 25 * 256 * 4);
    float* P6sf = (float*)alloc((size_t)40 * 25 * 256 * 4);
    float* P7xf = (float*)alloc((size_t)8  * 9  * 256 * 4);
    float* P7sf = (float*)alloc((size_t)40 * 9  * 256 * 4);
    u16* Qb   = (u16*)alloc((size_t)8  * 1600 * 256 * 2);
    u16* Kb   = (u16*)alloc((size_t)40 * 1600 * 256 * 2);
    u16* sPeT = (u16*)alloc((size_t)40 * 256 * 1664 * 2);
    float* lsum = (float*)alloc((size_t)40 * 1664 * 4);

    if (off > ws_size) return;  // visible failure rather than corruption

    hipMemsetAsync(d_out, 0, (size_t)out_size * 4, stream);
    hipMemsetAsync(P6xf, 0, (size_t)8  * 25 * 256 * 4, stream);
    hipMemsetAsync(P6sf, 0, (size_t)40 * 25 * 256 * 4, stream);
    hipMemsetAsync(P7xf, 0, (size_t)8  * 9  * 256 * 4, stream);
    hipMemsetAsync(P7sf, 0, (size_t)40 * 9  * 256 * 4, stream);

    // ---- weight prep ----
    cast1d<<<dim3(512),  256, 0, stream>>>(w31, w31b, 256L * 512);
    cast1d<<<dim3(1024), 256, 0, stream>>>(w41, w41b, 256L * 1024);
    cast1d<<<dim3(2048), 256, 0, stream>>>(w51, w51b, 256L * 2048);
    cast1d<<<dim3(256),  256, 0, stream>>>(wq, wqb, 256L * 256);
    cast1d<<<dim3(256),  256, 0, stream>>>(wk, wkb, 256L * 256);
    reorder_w3<<<dim3(2304),  256, 0, stream>>>(w32, w32b, 256);
    reorder_w3<<<dim3(2304),  256, 0, stream>>>(w42, w42b, 256);
    reorder_w3<<<dim3(2304),  256, 0, stream>>>(w52, w52b, 256);
    reorder_w3<<<dim3(18432), 256, 0, stream>>>(w6, w6b, 2048);
    reorder_w3<<<dim3(2304),  256, 0, stream>>>(w7, w7b, 256);

    // ---- input transposes to channel-last bf16 ----
    transp_cast<<<dim3(50, 16, 8),  256, 0, stream>>>(C3, X3t, 512, 1600);
    transp_cast<<<dim3(13, 32, 8),  256, 0, stream>>>(C4, X4t, 1024, 400);
    transp_cast<<<dim3(4,  64, 8),  256, 0, stream>>>(C5, X5t, 2048, 100);
    transp_cast<<<dim3(50, 16, 40), 256, 0, stream>>>(S3, S3t, 512, 1600);
    transp_cast<<<dim3(13, 32, 40), 256, 0, stream>>>(S4, S4t, 1024, 400);
    transp_cast<<<dim3(4,  64, 40), 256, 0, stream>>>(S5, S5t, 2048, 100);

    auto gemm = [&](const u16* A, const u16* BT, const float* bias,
                    u16* obf, float* oat, const float* ls,
                    int M, int K, int KS, int flags, int zoff,
                    long sA, long sBT, long sBF, long sAT, int nbz) {
        dim3 g((unsigned)((M + 127) / 128), (unsigned)(2 * KS), (unsigned)nbz);
        gemm_nt<<<g, 256, 0, stream>>>(A, BT, bias, obf, oat, ls, M, K, KS, flags, zoff,
                                       sA, sBT, sBF, sAT);
    };

    // ---- lateral 1x1 convs (z merged into M) ----
    gemm(X3t, w31b, b31, P3x, 0, 0, 12800, 512,  1, FLAG_BF16, 0, 0, 0, 0, 0, 1);
    gemm(X4t, w41b, b41, P4x, 0, 0, 3200,  1024, 1, FLAG_BF16, 0, 0, 0, 0, 0, 1);
    gemm(X5t, w51b, b51, P5x, 0, 0, 800,   2048, 1, FLAG_BF16, 0, 0, 0, 0, 0, 1);
    gemm(S3t, w31b, b31, P3s, 0, 0, 64000, 512,  1, FLAG_BF16, 0, 0, 0, 0, 0, 1);
    gemm(S4t, w41b, b41, P4s, 0, 0, 16000, 1024, 1, FLAG_BF16, 0, 0, 0, 0, 0, 1);
    gemm(S5t, w51b, b51, P5s, 0, 0, 4000,  2048, 1, FLAG_BF16, 0, 0, 0, 0, 0, 1);

    const size_t lvl_off[5] = {0, 6553600, 8192000, 8601600, 8704000};

    // ---- P6/P7 heads (stride-2 convs, split-K GEMMs) ----
    im2col_s2<<<dim3(25, 8), 256, 0, stream>>>(X5t, imcol, 10, 10, 5, 5, 2048, 0);
    gemm(imcol, w6b, b6, 0, P6xf, 0, 200, 18432, 8, FLAG_AT, 0, 0, 0, 0, 0, 1);
    im2col_s2<<<dim3(25, 40), 256, 0, stream>>>(S5t, imcol, 10, 10, 5, 5, 2048, 0);
    gemm(imcol, w6b, b6, 0, P6sf, 0, 1000, 18432, 8, FLAG_AT, 0, 0, 0, 0, 0, 1);
    cast_store<<<dim3(1, 8, 8),  256, 0, stream>>>(P6xf, q6, out + lvl_off[3], 25, 0);
    cast_store<<<dim3(1, 8, 40), 256, 0, stream>>>(P6sf, P6sb, 0, 25, 0);
    im2col_s2<<<dim3(9, 8), 256, 0, stream>>>(q6, imcol, 5, 5, 3, 3, 256, 1);
    gemm(imcol, w7b, b7, 0, P7xf, 0, 72, 2304, 4, FLAG_AT, 0, 0, 0, 0, 0, 1);
    im2col_s2<<<dim3(9, 40), 256, 0, stream>>>(P6sb, imcol, 5, 5, 3, 3, 256, 1);
    gemm(imcol, w7b, b7, 0, P7sf, 0, 360, 2304, 4, FLAG_AT, 0, 0, 0, 0, 0, 1);
    cast_store<<<dim3(1, 8, 8),  256, 0, stream>>>(P7xf, q7, out + lvl_off[4], 9, 0);
    cast_store<<<dim3(1, 8, 40), 256, 0, stream>>>(P7sf, P7sb, 0, 9, 0);

    // ---- query-side FPN ----
    up2add<<<dim3(400, 8),  256, 0, stream>>>(P4x, P5x, 20, 20);
    up2add<<<dim3(1600, 8), 256, 0, stream>>>(P3x, P4x, 40, 40);

    // ---- query-side 3x3 convs (split-K -> convf32 -> q bf16 + d_out cf) ----
    im2col_s1<<<dim3(100, 8), 256, 0, stream>>>(P5x, imcol, 10, 10);
    hipMemsetAsync(convf32, 0, (size_t)8 * 100 * 256 * 4, stream);
    gemm(imcol, w52b, b52, 0, convf32, 0, 800, 2304, 4, FLAG_AT, 0, 0, 0, 0, 0, 1);
    cast_store<<<dim3(4, 8, 8), 256, 0, stream>>>(convf32, q5, out + lvl_off[2], 100, 0);

    im2col_s1<<<dim3(400, 8), 256, 0, stream>>>(P4x, imcol, 20, 20);
    hipMemsetAsync(convf32, 0, (size_t)8 * 400 * 256 * 4, stream);
    gemm(imcol, w42b, b42, 0, convf32, 0, 3200, 2304, 4, FLAG_AT, 0, 0, 0, 0, 0, 1);
    cast_store<<<dim3(13, 8, 8), 256, 0, stream>>>(convf32, q4, out + lvl_off[1], 400, 0);

    im2col_s1<<<dim3(1600, 8), 256, 0, stream>>>(P3x, imcol, 40, 40);
    hipMemsetAsync(convf32, 0, (size_t)8 * 1600 * 256 * 4, stream);
    gemm(imcol, w32b, b32, 0, convf32, 0, 12800, 2304, 4, FLAG_AT, 0, 0, 0, 0, 0, 1);
    cast_store<<<dim3(50, 8, 8), 256, 0, stream>>>(convf32, q3, out + lvl_off[0], 1600, 0);

    // ---- attention per level: QK+exp GEMM -> PV GEMM -> transpose-store ----
    const int Ls[5]    = {1600, 400, 100, 25, 9};
    const int Kpads[5] = {1664, 512, 128, 128, 128};
    u16* qbuf[5] = {q3, q4, q5, q6, q7};
    u16* sbuf[5] = {P3s, P4s, P5s, P6sb, P7sb};
    for (int lv = 0; lv < 5; ++lv) {
        int L = Ls[lv], Kpad = Kpads[lv];
        add_pe<<<dim3(L, 40), 256, 0, stream>>>(sbuf[lv], L);
        transp_bf<<<dim3(Kpad / 32, 8, 40), 256, 0, stream>>>(sbuf[lv], sPeT, L, Kpad);
        gemm(qbuf[lv], wqb, bq, Qb, 0, 0, 8 * L,  256, 1, FLAG_BF16, 0, 0, 0, 0, 0, 1);
        gemm(sbuf[lv], wkb, bk, Kb, 0, 0, 40 * L, 256, 1, FLAG_BF16, 0, 0, 0, 0, 0, 1);
        hipMemsetAsync(lsum, 0, (size_t)40 * 1664 * 4, stream);
        int chunk = (lv == 0) ? 20 : 40;
        for (int c0 = 0; c0 < 40; c0 += chunk) {
            int nb = chunk / 5;
            hipMemsetAsync(attnf32, 0, (size_t)nb * L * 256 * 4, stream);
            dim3 gq((unsigned)((L + 127) / 128), (unsigned)(Kpad / 128), (unsigned)chunk);
            gemm_qk_exp<<<gq, 256, 0, stream>>>(Qb, Kb, expS, lsum, L, Kpad, c0);
            gemm(expS, sPeT, 0, 0, attnf32, lsum, L, Kpad, 1, FLAG_PV, c0,
                 (long)L * Kpad, (long)256 * Kpad, 0, (long)L * 256, chunk);
            cast_store<<<dim3((L + 31) / 32, 8, nb), 256, 0, stream>>>(
                attnf32, 0, out + lvl_off[lv] + (size_t)(c0 / 5) * 512 * L, L, 256);
        }
    }
}

// Round 3
// 1943.315 us; speedup vs baseline: 1.2004x; 1.1943x over previous
//
#include <hip/hip_runtime.h>

typedef unsigned short u16;
typedef __attribute__((ext_vector_type(8))) short short8;
typedef __attribute__((ext_vector_type(4))) float floatx4;

#define DEV static __device__ __forceinline__

DEV u16 f2bf(float f) {
    union { float f; unsigned u; } v; v.f = f;
    unsigned r = v.u + 0x7fff + ((v.u >> 16) & 1);
    return (u16)(r >> 16);
}
DEV float bf2f(u16 h) {
    union { unsigned u; float f; } v; v.u = ((unsigned)h) << 16;
    return v.f;
}

DEV void load_lds16(const u16* g, u16* l) {
    __builtin_amdgcn_global_load_lds(
        (const __attribute__((address_space(1))) void*)g,
        (__attribute__((address_space(3))) void*)l, 16, 0, 0);
}

#define FLAG_BF16 1
#define FLAG_AT   4
#define FLAG_PV   8

// ---------------------------------------------------------------------------
// NT GEMM: C[M][256] = A[M][K] * BT[256][K]^T (+bias). bf16 in, f32 acc.
// 128x128 tile, BK=64. Coalesced staging: each wave-load = 8 rows x 8 pieces
// (128 contiguous B per 8-lane group, 100% line use), XOR-swizzled pieces so
// ds_read_b128 fragment reads are 2-way-conflict (free). K, Kper % 64 == 0.
// ---------------------------------------------------------------------------
__global__ __launch_bounds__(256, 2) void gemm_nt(
    const u16* __restrict__ A, const u16* __restrict__ BT,
    const float* __restrict__ bias,
    u16* __restrict__ obf, float* __restrict__ oat, const float* __restrict__ lsum,
    int M, int K, int KS, int flags, int zoff,
    long sA, long sBT, long sBF, long sAT)
{
    __shared__ u16 Al[8192];   // [row(128)][slot(8)*8] ; slot = piece ^ (row&7)
    __shared__ u16 Bl[8192];
    const int tid = threadIdx.x, lane = tid & 63, w = tid >> 6;
    const int wr = w & 1, wc = w >> 1;
    const int col16 = lane & 15, quad = (lane >> 4) & 3;
    const int lrow = lane >> 3;                 // 0..7 within 8-row group
    const int lpc  = (lane & 7) ^ lrow;         // swizzled piece index 0..7
    const int sw   = col16 & 7;                 // reader-side swizzle key
    const int mt = blockIdx.x, nt = blockIdx.y & 1, ks = blockIdx.y >> 1, z = blockIdx.z;
    const int sb = zoff + z;
    const int m0 = mt * 128, n0 = nt * 128;
    const u16* Ab = A + (size_t)z * sA;
    const u16* Bb = BT + (size_t)sb * sBT;
    const int Kper = K / KS;
    const int kbeg = ks * Kper;
    const floatx4 fz = {0.f, 0.f, 0.f, 0.f};

    floatx4 acc[4][4];
#pragma unroll
    for (int i = 0; i < 4; ++i)
#pragma unroll
        for (int j = 0; j < 4; ++j) acc[i][j] = fz;

    for (int kb = 0; kb < Kper; kb += 64) {
        const int k0 = kbeg + kb;
        __syncthreads();
#pragma unroll
        for (int j = 0; j < 4; ++j) {
            int g = w * 4 + j;                  // 0..15 (8-row group)
            int rloc = g * 8 + lrow;            // 0..127
            int ra = m0 + rloc; ra = ra < M ? ra : (M - 1);
            load_lds16(Ab + (size_t)ra * K + k0 + lpc * 8, &Al[g * 512]);
            int rb = n0 + rloc;                 // BT always has 256 rows
            load_lds16(Bb + (size_t)rb * K + k0 + lpc * 8, &Bl[g * 512]);
        }
        __syncthreads();
#pragma unroll
        for (int s = 0; s < 2; ++s) {
            short8 af[4], bfr[4];
#pragma unroll
            for (int i = 0; i < 4; ++i) {
                int r = wr * 64 + i * 16 + col16;
                af[i] = *(const short8*)&Al[r * 64 + (((s * 4 + quad) ^ sw) * 8)];
            }
#pragma unroll
            for (int j = 0; j < 4; ++j) {
                int r = wc * 64 + j * 16 + col16;
                bfr[j] = *(const short8*)&Bl[r * 64 + (((s * 4 + quad) ^ sw) * 8)];
            }
#pragma unroll
            for (int i = 0; i < 4; ++i)
#pragma unroll
                for (int j = 0; j < 4; ++j)
                    acc[i][j] = __builtin_amdgcn_mfma_f32_16x16x32_bf16(af[i], bfr[j], acc[i][j], 0, 0, 0);
        }
    }

#pragma unroll
    for (int j = 0; j < 4; ++j) {
        int gcol = n0 + wc * 64 + j * 16 + col16;
        float bv = (bias && ks == 0) ? bias[gcol] : 0.f;
#pragma unroll
        for (int i = 0; i < 4; ++i) {
            int rowb = m0 + wr * 64 + i * 16 + quad * 4;
#pragma unroll
            for (int r = 0; r < 4; ++r) {
                int row = rowb + r;
                if (row < M) {
                    float v = acc[i][j][r] + bv;
                    if (flags & FLAG_BF16) obf[(size_t)z * sBF + (size_t)row * 256 + gcol] = f2bf(v);
                    if (flags & FLAG_AT)   atomicAdd(&oat[(size_t)z * sAT + (size_t)row * 256 + gcol], v);
                    if (flags & FLAG_PV) {
                        int bl = z / 5;   // chunk-local batch (zoff % 5 == 0)
                        float sc = 0.2f / lsum[(size_t)sb * 1664 + row];
                        atomicAdd(&oat[(size_t)bl * sAT + (size_t)row * 256 + gcol], v * sc);
                    }
                }
            }
        }
    }
}

// ---------------------------------------------------------------------------
// QK^T with fused exp epilogue. A=Q[b][M][256] (b=sb/5), BT=K[sb][M][256].
// Same coalesced/swizzled staging (K=256 -> 4 iters). Writes expS bf16
// [z][M][Kpad] (cols >= M zeroed) + atomic row sums into lsum[sb][row].
// ---------------------------------------------------------------------------
__global__ __launch_bounds__(256, 2) void gemm_qk_exp(
    const u16* __restrict__ Q, const u16* __restrict__ Km,
    u16* __restrict__ eS, float* __restrict__ lsum,
    int M, int Kpad, int zoff)
{
    __shared__ u16 Al[8192];
    __shared__ u16 Bl[8192];
    const int tid = threadIdx.x, lane = tid & 63, w = tid >> 6;
    const int wr = w & 1, wc = w >> 1;
    const int col16 = lane & 15, quad = (lane >> 4) & 3;
    const int lrow = lane >> 3;
    const int lpc  = (lane & 7) ^ lrow;
    const int sw   = col16 & 7;
    const int mt = blockIdx.x, nt = blockIdx.y, z = blockIdx.z;
    const int sb = zoff + z;
    const int m0 = mt * 128, n0 = nt * 128;
    const u16* Ab = Q + (size_t)(sb / 5) * M * 256;
    const u16* Bb = Km + (size_t)sb * M * 256;
    u16* eSb = eS + (size_t)z * M * Kpad;
    const floatx4 fz = {0.f, 0.f, 0.f, 0.f};

    floatx4 acc[4][4];
#pragma unroll
    for (int i = 0; i < 4; ++i)
#pragma unroll
        for (int j = 0; j < 4; ++j) acc[i][j] = fz;

    for (int k0 = 0; k0 < 256; k0 += 64) {
        __syncthreads();
#pragma unroll
        for (int j = 0; j < 4; ++j) {
            int g = w * 4 + j;
            int rloc = g * 8 + lrow;
            int ra = m0 + rloc; ra = ra < M ? ra : (M - 1);
            load_lds16(Ab + (size_t)ra * 256 + k0 + lpc * 8, &Al[g * 512]);
            int rb = n0 + rloc; rb = rb < M ? rb : (M - 1);
            load_lds16(Bb + (size_t)rb * 256 + k0 + lpc * 8, &Bl[g * 512]);
        }
        __syncthreads();
#pragma unroll
        for (int s = 0; s < 2; ++s) {
            short8 af[4], bfr[4];
#pragma unroll
            for (int i = 0; i < 4; ++i) {
                int r = wr * 64 + i * 16 + col16;
                af[i] = *(const short8*)&Al[r * 64 + (((s * 4 + quad) ^ sw) * 8)];
            }
#pragma unroll
            for (int j = 0; j < 4; ++j) {
                int r = wc * 64 + j * 16 + col16;
                bfr[j] = *(const short8*)&Bl[r * 64 + (((s * 4 + quad) ^ sw) * 8)];
            }
#pragma unroll
            for (int i = 0; i < 4; ++i)
#pragma unroll
                for (int j = 0; j < 4; ++j)
                    acc[i][j] = __builtin_amdgcn_mfma_f32_16x16x32_bf16(af[i], bfr[j], acc[i][j], 0, 0, 0);
        }
    }

#pragma unroll
    for (int i = 0; i < 4; ++i) {
#pragma unroll
        for (int r = 0; r < 4; ++r) {
            int row = m0 + wr * 64 + i * 16 + quad * 4 + r;
            float s = 0.f;
#pragma unroll
            for (int j = 0; j < 4; ++j) {
                int gcol = n0 + wc * 64 + j * 16 + col16;
                float v = 0.f;
                if (row < M && gcol < M) v = __expf(acc[i][j][r] * 0.0625f);
                u16 h = f2bf(v);
                if (row < M) eSb[(size_t)row * Kpad + gcol] = h;
                s += bf2f(h);
            }
            s += __shfl_xor(s, 1); s += __shfl_xor(s, 2);
            s += __shfl_xor(s, 4); s += __shfl_xor(s, 8);
            if ((lane & 15) == 0 && row < M)
                atomicAdd(&lsum[(size_t)sb * 1664 + row], s);
        }
    }
}

// ------------------- glue kernels -------------------

// [z][C][HW] f32 -> [z][HW][C] bf16 (tiled 32x32)
__global__ void transp_cast(const float* __restrict__ in, u16* __restrict__ out, int C, int HW) {
    __shared__ float t[32][33];
    int z = blockIdx.z;
    int p0 = blockIdx.x * 32, c0 = blockIdx.y * 32;
    int tx = threadIdx.x & 31, ty = threadIdx.x >> 5;
    const float* ib = in + (size_t)z * C * HW;
    u16* ob = out + (size_t)z * HW * C;
#pragma unroll
    for (int i = 0; i < 4; ++i) {
        int c = c0 + ty + i * 8, p = p0 + tx;
        t[ty + i * 8][tx] = (p < HW) ? ib[(size_t)c * HW + p] : 0.f;
    }
    __syncthreads();
#pragma unroll
    for (int i = 0; i < 4; ++i) {
        int p = p0 + ty + i * 8, c = c0 + tx;
        if (p < HW) ob[(size_t)p * C + c] = f2bf(t[tx][ty + i * 8]);
    }
}

// support [z][L][256] bf16 -> V^T [z][256][Kpad] bf16, cols >= L zeroed
__global__ void transp_bf(const u16* __restrict__ in, u16* __restrict__ out, int L, int Kpad) {
    __shared__ u16 t[32][33];
    int z = blockIdx.z;
    int l0 = blockIdx.x * 32, c0 = blockIdx.y * 32;
    int tx = threadIdx.x & 31, ty = threadIdx.x >> 5;
    const u16* ib = in + (size_t)z * L * 256;
    u16* ob = out + (size_t)z * 256 * Kpad;
#pragma unroll
    for (int i = 0; i < 4; ++i) {
        int l = l0 + ty + i * 8;
        t[ty + i * 8][tx] = (l < L) ? ib[(size_t)l * 256 + c0 + tx] : (u16)0;
    }
    __syncthreads();
#pragma unroll
    for (int i = 0; i < 4; ++i) {
        int l = l0 + tx, c = c0 + ty + i * 8;
        ob[(size_t)c * Kpad + l] = t[tx][ty + i * 8];
    }
}

__global__ void cast1d(const float* __restrict__ in, u16* __restrict__ out, long n) {
    long i = (long)blockIdx.x * 256 + threadIdx.x;
    if (i < n) out[i] = f2bf(in[i]);
}

// W [256][C][9] f32 -> [256][9][C] bf16
__global__ void reorder_w3(const float* __restrict__ in, u16* __restrict__ out, int C) {
    long i = (long)blockIdx.x * 256 + threadIdx.x;
    int co = (int)(i / (9L * C));
    int r = (int)(i % (9L * C));
    int t = r / C, c = r % C;
    out[i] = f2bf(in[((size_t)co * C + c) * 9 + t]);
}

// 3x3 s1 p1 im2col, C=256, channel-last bf16 -> rows [z*HW][2304]
__global__ void im2col_s1(const u16* __restrict__ in, u16* __restrict__ out, int H, int Wd) {
    int z = blockIdx.y, p = blockIdx.x, c = threadIdx.x;
    int y = p / Wd, x = p % Wd;
    const u16* ib = in + (size_t)z * H * Wd * 256;
    u16* ob = out + ((size_t)z * H * Wd + p) * 2304;
#pragma unroll
    for (int t = 0; t < 9; ++t) {
        int ys = y + t / 3 - 1, xs = x + t % 3 - 1;
        u16 v = 0;
        if (ys >= 0 && ys < H && xs >= 0 && xs < Wd) v = ib[((size_t)ys * Wd + xs) * 256 + c];
        ob[t * 256 + c] = v;
    }
}

// 3x3 stride-2 p1 im2col, generic C, optional relu on read
__global__ void im2col_s2(const u16* __restrict__ in, u16* __restrict__ out,
                          int Hin, int Win, int Hout, int Wout, int C, int relu) {
    int z = blockIdx.y, p = blockIdx.x, tid = threadIdx.x;
    int oy = p / Wout, ox = p % Wout;
    const u16* ib = in + (size_t)z * Hin * Win * C;
    u16* ob = out + ((size_t)z * Hout * Wout + p) * (9L * C);
    for (int t = 0; t < 9; ++t) {
        int ys = oy * 2 + t / 3 - 1, xs = ox * 2 + t % 3 - 1;
        bool ok = (ys >= 0 && ys < Hin && xs >= 0 && xs < Win);
        for (int c = tid; c < C; c += 256) {
            u16 v = 0;
            if (ok) {
                v = ib[((size_t)ys * Win + xs) * C + c];
                if (relu && (v & 0x8000)) v = 0;
            }
            ob[(size_t)t * C + c] = v;
        }
    }
}

// big[p][c] += small[p/2-map][c]  (nearest 2x upsample add, in place, bf16)
__global__ void up2add(u16* __restrict__ big, const u16* __restrict__ small, int Hb, int Wb) {
    int z = blockIdx.y, p = blockIdx.x, c = threadIdx.x;
    int y = p / Wb, x = p % Wb;
    size_t bi = ((size_t)z * Hb * Wb + p) * 256 + c;
    size_t si = ((size_t)z * (Hb / 2) * (Wb / 2) + (size_t)(y >> 1) * (Wb / 2) + (x >> 1)) * 256 + c;
    big[bi] = f2bf(bf2f(big[bi]) + bf2f(small[si]));
}

// s[l][c] += pe(l,c), in place bf16
__global__ void add_pe(u16* __restrict__ s, int L) {
    int z = blockIdx.y, l = blockIdx.x, c = threadIdx.x;
    size_t i = ((size_t)z * L + l) * 256 + c;
    float arg = (float)l * expf(-0.035977892078031971f * (float)(c & ~1));
    float pe = (c & 1) ? cosf(arg) : sinf(arg);
    s[i] = f2bf(bf2f(s[i]) + pe);
}

// in f32 [z][M][256] -> optional bf16 qout (same layout, coalesced) and
// optional f32 d_out channel-first [z][512][M] at channel offset choff,
// via LDS 32x32 tile transpose (coalesced stores).
__global__ void cast_store(const float* __restrict__ in, u16* __restrict__ qout,
                           float* __restrict__ dout, int M, int choff) {
    __shared__ float t[32][33];
    int z = blockIdx.z, p0 = blockIdx.x * 32, c0 = blockIdx.y * 32;
    int tx = threadIdx.x & 31, ty = threadIdx.x >> 5;
#pragma unroll
    for (int i = 0; i < 4; ++i) {
        int p = p0 + ty + i * 8, c = c0 + tx;
        float v = 0.f;
        if (p < M) v = in[((size_t)z * M + p) * 256 + c];
        t[ty + i * 8][tx] = v;
        if (qout && p < M) qout[((size_t)z * M + p) * 256 + c] = f2bf(v);
    }
    __syncthreads();
    if (dout) {
#pragma unroll
        for (int i = 0; i < 4; ++i) {
            int p = p0 + tx, c = c0 + ty + i * 8;
            if (p < M) dout[((size_t)z * 512 + choff + c) * M + p] = t[tx][ty + i * 8];
        }
    }
}

// ---------------------------------------------------------------------------
extern "C" void kernel_launch(void* const* d_in, const int* in_sizes, int n_in,
                              void* d_out, int out_size, void* d_ws, size_t ws_size,
                              hipStream_t stream)
{
    (void)in_sizes; (void)n_in;
    const float* C3 = (const float*)d_in[0];
    const float* C4 = (const float*)d_in[1];
    const float* C5 = (const float*)d_in[2];
    const float* S3 = (const float*)d_in[3];
    const float* S4 = (const float*)d_in[4];
    const float* S5 = (const float*)d_in[5];
    const float* w31 = (const float*)d_in[6];  const float* b31 = (const float*)d_in[7];
    const float* w32 = (const float*)d_in[8];  const float* b32 = (const float*)d_in[9];
    const float* w41 = (const float*)d_in[10]; const float* b41 = (const float*)d_in[11];
    const float* w42 = (const float*)d_in[12]; const float* b42 = (const float*)d_in[13];
    const float* w51 = (const float*)d_in[14]; const float* b51 = (const float*)d_in[15];
    const float* w52 = (const float*)d_in[16]; const float* b52 = (const float*)d_in[17];
    const float* w6  = (const float*)d_in[18]; const float* b6  = (const float*)d_in[19];
    const float* w7  = (const float*)d_in[20]; const float* b7  = (const float*)d_in[21];
    const float* wq  = (const float*)d_in[22]; const float* bq  = (const float*)d_in[23];
    const float* wk  = (const float*)d_in[24]; const float* bk  = (const float*)d_in[25];
    float* out = (float*)d_out;

    char* base = (char*)d_ws;
    size_t off = 0;
    auto alloc = [&](size_t bytes) -> void* {
        void* r = base + off;
        off = (off + bytes + 255) & ~(size_t)255;
        return r;
    };

    // ---- arena (time-multiplexed): transposes -> imcol+convf32 -> expS+attnf32
    char* arena = (char*)alloc(117964800);
    u16* X3t = (u16*)(arena + 0);          //  8*1600*512*2  = 13,107,200
    u16* X4t = (u16*)(arena + 13107200);   //  8* 400*1024*2 =  6,553,600
    u16* S3t = (u16*)(arena + 19660800);   // 40*1600*512*2  = 65,536,000
    u16* S4t = (u16*)(arena + 85196800);   // 40* 400*1024*2 = 32,768,000
    u16*   imcol   = (u16*)(arena + 0);           // <= 58,982,400
    float* convf32 = (float*)(arena + 58982400);  // <= 13,107,200
    u16*   expS    = (u16*)(arena + 0);           // <= 106,496,000
    float* attnf32 = (float*)(arena + 106496000); // <=  6,553,600 (chunked)

    u16* X5t = (u16*)alloc((size_t)8  * 100 * 2048 * 2);
    u16* S5t = (u16*)alloc((size_t)40 * 100 * 2048 * 2);

    u16* w31b = (u16*)alloc(256L * 512 * 2);
    u16* w41b = (u16*)alloc(256L * 1024 * 2);
    u16* w51b = (u16*)alloc(256L * 2048 * 2);
    u16* wqb  = (u16*)alloc(256L * 256 * 2);
    u16* wkb  = (u16*)alloc(256L * 256 * 2);
    u16* w32b = (u16*)alloc(256L * 9 * 256 * 2);
    u16* w42b = (u16*)alloc(256L * 9 * 256 * 2);
    u16* w52b = (u16*)alloc(256L * 9 * 256 * 2);
    u16* w6b  = (u16*)alloc(256L * 9 * 2048 * 2);
    u16* w7b  = (u16*)alloc(256L * 9 * 256 * 2);

    u16* P3x = (u16*)alloc((size_t)8  * 1600 * 256 * 2);
    u16* P4x = (u16*)alloc((size_t)8  * 400  * 256 * 2);
    u16* P5x = (u16*)alloc((size_t)8  * 100  * 256 * 2);
    u16* P3s = (u16*)alloc((size_t)40 * 1600 * 256 * 2);
    u16* P4s = (u16*)alloc((size_t)40 * 400  * 256 * 2);
    u16* P5s = (u16*)alloc((size_t)40 * 100  * 256 * 2);
    u16* q3  = (u16*)alloc((size_t)8 * 1600 * 256 * 2);
    u16* q4  = (u16*)alloc((size_t)8 * 400  * 256 * 2);
    u16* q5  = (u16*)alloc((size_t)8 * 100  * 256 * 2);
    u16* q6  = (u16*)alloc((size_t)8 * 25   * 256 * 2);
    u16* q7  = (u16*)alloc((size_t)8 * 9    * 256 * 2);
    u16* P6sb = (u16*)alloc((size_t)40 * 25 * 256 * 2);
    u16* P7sb = (u16*)alloc((size_t)40 * 9  * 256 * 2);
    float* P6xf = (float*)alloc((size_t)8  * 25 * 256 * 4);
    float* P6sf = (float*)alloc((size_t)40 * 25 * 256 * 4);
    float* P7xf = (float*)alloc((size_t)8  * 9  * 256 * 4);
    float* P7sf = (float*)alloc((size_t)40 * 9  * 256 * 4);
    u16* Qb   = (u16*)alloc((size_t)8  * 1600 * 256 * 2);
    u16* Kb   = (u16*)alloc((size_t)40 * 1600 * 256 * 2);
    u16* sPeT = (u16*)alloc((size_t)40 * 256 * 1664 * 2);
    float* lsum = (float*)alloc((size_t)40 * 1664 * 4);

    if (off > ws_size) return;  // visible failure rather than corruption

    hipMemsetAsync(d_out, 0, (size_t)out_size * 4, stream);
    hipMemsetAsync(P6xf, 0, (size_t)8  * 25 * 256 * 4, stream);
    hipMemsetAsync(P6sf, 0, (size_t)40 * 25 * 256 * 4, stream);
    hipMemsetAsync(P7xf, 0, (size_t)8  * 9  * 256 * 4, stream);
    hipMemsetAsync(P7sf, 0, (size_t)40 * 9  * 256 * 4, stream);

    // ---- weight prep ----
    cast1d<<<dim3(512),  256, 0, stream>>>(w31, w31b, 256L * 512);
    cast1d<<<dim3(1024), 256, 0, stream>>>(w41, w41b, 256L * 1024);
    cast1d<<<dim3(2048), 256, 0, stream>>>(w51, w51b, 256L * 2048);
    cast1d<<<dim3(256),  256, 0, stream>>>(wq, wqb, 256L * 256);
    cast1d<<<dim3(256),  256, 0, stream>>>(wk, wkb, 256L * 256);
    reorder_w3<<<dim3(2304),  256, 0, stream>>>(w32, w32b, 256);
    reorder_w3<<<dim3(2304),  256, 0, stream>>>(w42, w42b, 256);
    reorder_w3<<<dim3(2304),  256, 0, stream>>>(w52, w52b, 256);
    reorder_w3<<<dim3(18432), 256, 0, stream>>>(w6, w6b, 2048);
    reorder_w3<<<dim3(2304),  256, 0, stream>>>(w7, w7b, 256);

    // ---- input transposes to channel-last bf16 ----
    transp_cast<<<dim3(50, 16, 8),  256, 0, stream>>>(C3, X3t, 512, 1600);
    transp_cast<<<dim3(13, 32, 8),  256, 0, stream>>>(C4, X4t, 1024, 400);
    transp_cast<<<dim3(4,  64, 8),  256, 0, stream>>>(C5, X5t, 2048, 100);
    transp_cast<<<dim3(50, 16, 40), 256, 0, stream>>>(S3, S3t, 512, 1600);
    transp_cast<<<dim3(13, 32, 40), 256, 0, stream>>>(S4, S4t, 1024, 400);
    transp_cast<<<dim3(4,  64, 40), 256, 0, stream>>>(S5, S5t, 2048, 100);

    auto gemm = [&](const u16* A, const u16* BT, const float* bias,
                    u16* obf, float* oat, const float* ls,
                    int M, int K, int KS, int flags, int zoff,
                    long sA, long sBT, long sBF, long sAT, int nbz) {
        dim3 g((unsigned)((M + 127) / 128), (unsigned)(2 * KS), (unsigned)nbz);
        gemm_nt<<<g, 256, 0, stream>>>(A, BT, bias, obf, oat, ls, M, K, KS, flags, zoff,
                                       sA, sBT, sBF, sAT);
    };

    // ---- lateral 1x1 convs (z merged into M) ----
    gemm(X3t, w31b, b31, P3x, 0, 0, 12800, 512,  1, FLAG_BF16, 0, 0, 0, 0, 0, 1);
    gemm(X4t, w41b, b41, P4x, 0, 0, 3200,  1024, 1, FLAG_BF16, 0, 0, 0, 0, 0, 1);
    gemm(X5t, w51b, b51, P5x, 0, 0, 800,   2048, 1, FLAG_BF16, 0, 0, 0, 0, 0, 1);
    gemm(S3t, w31b, b31, P3s, 0, 0, 64000, 512,  1, FLAG_BF16, 0, 0, 0, 0, 0, 1);
    gemm(S4t, w41b, b41, P4s, 0, 0, 16000, 1024, 1, FLAG_BF16, 0, 0, 0, 0, 0, 1);
    gemm(S5t, w51b, b51, P5s, 0, 0, 4000,  2048, 1, FLAG_BF16, 0, 0, 0, 0, 0, 1);

    const size_t lvl_off[5] = {0, 6553600, 8192000, 8601600, 8704000};

    // ---- P6/P7 heads (stride-2 convs, split-K GEMMs; Kper % 64 == 0) ----
    im2col_s2<<<dim3(25, 8), 256, 0, stream>>>(X5t, imcol, 10, 10, 5, 5, 2048, 0);
    gemm(imcol, w6b, b6, 0, P6xf, 0, 200, 18432, 8, FLAG_AT, 0, 0, 0, 0, 0, 1);
    im2col_s2<<<dim3(25, 40), 256, 0, stream>>>(S5t, imcol, 10, 10, 5, 5, 2048, 0);
    gemm(imcol, w6b, b6, 0, P6sf, 0, 1000, 18432, 8, FLAG_AT, 0, 0, 0, 0, 0, 1);
    cast_store<<<dim3(1, 8, 8),  256, 0, stream>>>(P6xf, q6, out + lvl_off[3], 25, 0);
    cast_store<<<dim3(1, 8, 40), 256, 0, stream>>>(P6sf, P6sb, 0, 25, 0);
    im2col_s2<<<dim3(9, 8), 256, 0, stream>>>(q6, imcol, 5, 5, 3, 3, 256, 1);
    gemm(imcol, w7b, b7, 0, P7xf, 0, 72, 2304, 4, FLAG_AT, 0, 0, 0, 0, 0, 1);
    im2col_s2<<<dim3(9, 40), 256, 0, stream>>>(P6sb, imcol, 5, 5, 3, 3, 256, 1);
    gemm(imcol, w7b, b7, 0, P7sf, 0, 360, 2304, 4, FLAG_AT, 0, 0, 0, 0, 0, 1);
    cast_store<<<dim3(1, 8, 8),  256, 0, stream>>>(P7xf, q7, out + lvl_off[4], 9, 0);
    cast_store<<<dim3(1, 8, 40), 256, 0, stream>>>(P7sf, P7sb, 0, 9, 0);

    // ---- query-side FPN ----
    up2add<<<dim3(400, 8),  256, 0, stream>>>(P4x, P5x, 20, 20);
    up2add<<<dim3(1600, 8), 256, 0, stream>>>(P3x, P4x, 40, 40);

    // ---- query-side 3x3 convs (split-K -> convf32 -> q bf16 + d_out cf) ----
    im2col_s1<<<dim3(100, 8), 256, 0, stream>>>(P5x, imcol, 10, 10);
    hipMemsetAsync(convf32, 0, (size_t)8 * 100 * 256 * 4, stream);
    gemm(imcol, w52b, b52, 0, convf32, 0, 800, 2304, 6, FLAG_AT, 0, 0, 0, 0, 0, 1);
    cast_store<<<dim3(4, 8, 8), 256, 0, stream>>>(convf32, q5, out + lvl_off[2], 100, 0);

    im2col_s1<<<dim3(400, 8), 256, 0, stream>>>(P4x, imcol, 20, 20);
    hipMemsetAsync(convf32, 0, (size_t)8 * 400 * 256 * 4, stream);
    gemm(imcol, w42b, b42, 0, convf32, 0, 3200, 2304, 4, FLAG_AT, 0, 0, 0, 0, 0, 1);
    cast_store<<<dim3(13, 8, 8), 256, 0, stream>>>(convf32, q4, out + lvl_off[1], 400, 0);

    im2col_s1<<<dim3(1600, 8), 256, 0, stream>>>(P3x, imcol, 40, 40);
    hipMemsetAsync(convf32, 0, (size_t)8 * 1600 * 256 * 4, stream);
    gemm(imcol, w32b, b32, 0, convf32, 0, 12800, 2304, 2, FLAG_AT, 0, 0, 0, 0, 0, 1);
    cast_store<<<dim3(50, 8, 8), 256, 0, stream>>>(convf32, q3, out + lvl_off[0], 1600, 0);

    // ---- attention per level: QK+exp GEMM -> PV GEMM -> transpose-store ----
    const int Ls[5]    = {1600, 400, 100, 25, 9};
    const int Kpads[5] = {1664, 512, 128, 128, 128};
    u16* qbuf[5] = {q3, q4, q5, q6, q7};
    u16* sbuf[5] = {P3s, P4s, P5s, P6sb, P7sb};
    for (int lv = 0; lv < 5; ++lv) {
        int L = Ls[lv], Kpad = Kpads[lv];
        add_pe<<<dim3(L, 40), 256, 0, stream>>>(sbuf[lv], L);
        transp_bf<<<dim3(Kpad / 32, 8, 40), 256, 0, stream>>>(sbuf[lv], sPeT, L, Kpad);
        gemm(qbuf[lv], wqb, bq, Qb, 0, 0, 8 * L,  256, 1, FLAG_BF16, 0, 0, 0, 0, 0, 1);
        gemm(sbuf[lv], wkb, bk, Kb, 0, 0, 40 * L, 256, 1, FLAG_BF16, 0, 0, 0, 0, 0, 1);
        hipMemsetAsync(lsum, 0, (size_t)40 * 1664 * 4, stream);
        int chunk = (lv == 0) ? 20 : 40;
        for (int c0 = 0; c0 < 40; c0 += chunk) {
            int nb = chunk / 5;
            hipMemsetAsync(attnf32, 0, (size_t)nb * L * 256 * 4, stream);
            dim3 gq((unsigned)((L + 127) / 128), (unsigned)(Kpad / 128), (unsigned)chunk);
            gemm_qk_exp<<<gq, 256, 0, stream>>>(Qb, Kb, expS, lsum, L, Kpad, c0);
            gemm(expS, sPeT, 0, 0, attnf32, lsum, L, Kpad, 1, FLAG_PV, c0,
                 (long)L * Kpad, (long)256 * Kpad, 0, (long)L * 256, chunk);
            cast_store<<<dim3((L + 31) / 32, 8, nb), 256, 0, stream>>>(
                attnf32, 0, out + lvl_off[lv] + (size_t)(c0 / 5) * 512 * L, L, 256);
        }
    }
}